// Round 8
// baseline (278.865 us; speedup 1.0000x reference)
//
#include <hip/hip_runtime.h>

typedef __bf16 bf16_t;
typedef bf16_t bf16x8 __attribute__((ext_vector_type(8)));
typedef float f32x4 __attribute__((ext_vector_type(4)));

#define NB 8
#define TT 2048
#define DIN 1024
#define HH 64
#define MM (NB * TT)

__device__ __forceinline__ unsigned short f2bf(float f) {
    unsigned int u = __float_as_uint(f);
    u += 0x7fffu + ((u >> 16) & 1u);   // round-to-nearest-even
    return (unsigned short)(u >> 16);
}

// async global->LDS, 16B per lane. LDS dest = base + lane*16 (linear);
// global src may be per-lane (16B-aligned). Exec-masked.
__device__ __forceinline__ void async16(void* l, const void* g) {
    __builtin_amdgcn_global_load_lds(
        (const __attribute__((address_space(1))) unsigned int*)g,
        (__attribute__((address_space(3))) unsigned int*)l, 16, 0, 0);
}

// Per-block dtype probe: low-bf16 exponent field of x words.
// fp32 data -> ~20% in range; bf16 -> ~100%. Returns 1 if fp32.
__device__ __forceinline__ int block_detect_f32(const unsigned int* __restrict__ xw,
                                                int tid, int* sflag) {
    if (tid < 64) {
        unsigned int u = xw[tid];
        unsigned int e = (u >> 7) & 0xFFu;
        unsigned long long m = __ballot(e >= 100u && e <= 150u);
        if (tid == 0) *sflag = (__popcll(m) < 48) ? 1 : 0;
    }
    __syncthreads();
    return *sflag;
}

// ------------------------------------------------------------------
// LDS-tiled W transpose: Wt[w*64+n][k] = W_w[k][n], bf16.
// Also zeroes the attn combine counters (block 0).
// ------------------------------------------------------------------
__global__ __launch_bounds__(256) void transpose_w_kernel(
    const void* __restrict__ Wq, const void* __restrict__ Wk,
    const void* __restrict__ Wv, const unsigned int* __restrict__ xw,
    unsigned short* __restrict__ Wt, int* __restrict__ ctr) {
    __shared__ int sflag;
    __shared__ unsigned short ts[64][68];
    const int tid = threadIdx.x;
    if (blockIdx.x == 0) ctr[tid] = 0;
    const int isf32 = block_detect_f32(xw, tid, &sflag);
    const int w = blockIdx.x >> 4, kt = blockIdx.x & 15;
    const void* W = (w == 0) ? Wq : (w == 1) ? Wk : Wv;
    const int kk = tid >> 4, nn = (tid & 15) * 4;
#pragma unroll
    for (int j = 0; j < 4; ++j) {
        int k = kk + j * 16;
        if (isf32) {
            float4 f = *(const float4*)((const float*)W + (size_t)(kt * 64 + k) * 64 + nn);
            ts[k][nn + 0] = f2bf(f.x); ts[k][nn + 1] = f2bf(f.y);
            ts[k][nn + 2] = f2bf(f.z); ts[k][nn + 3] = f2bf(f.w);
        } else {
            *(uint2*)&ts[k][nn] =
                *(const uint2*)((const unsigned short*)W + (size_t)(kt * 64 + k) * 64 + nn);
        }
    }
    __syncthreads();
    const int n = tid >> 2, k0 = (tid & 3) * 16;
    unsigned short tmp[16];
#pragma unroll
    for (int j = 0; j < 16; ++j) tmp[j] = ts[k0 + j][n];
    unsigned short* dst = Wt + (size_t)(w * 64 + n) * 1024 + kt * 64 + k0;
    *(uint4*)(dst + 0) = *(uint4*)&tmp[0];
    *(uint4*)(dst + 8) = *(uint4*)&tmp[8];
}

// ------------------------------------------------------------------
// Fused QKV projection v6: cut LDS insts/MFMA. Block = M-64 x N-96
// (nh = blockIdx.y), grid (256,2) = 512 blocks = 2/CU. Wave-tile
// 32x48: per wave-iter 4 A + 6 B ds_read_b128 -> 12 MFMA (0.83
// reads/MFMA vs 1.67 in v5). x converted fp32->bf16 BEFORE LDS
// (reg->cvt->ds_write_b128), halving x LDS bytes + A reads.
// W staged via async16 from Wt (L2-resident).
// ------------------------------------------------------------------
#define XR 72      /* x LDS row stride in bf16 elems (144 B) */
#define WROWC 9    /* W LDS row = 9 chunks = 144 B (128 payload) */

__global__ __launch_bounds__(256, 2) void proj_kernel(
    const void* __restrict__ xraw, const unsigned short* __restrict__ Wt,
    unsigned short* __restrict__ qbuf, unsigned short* __restrict__ kbuf,
    unsigned short* __restrict__ vtbuf) {
    __shared__ int sflag;
    __shared__ __align__(16) unsigned short xs[64 * XR];            // 9216 B
    __shared__ __align__(16) unsigned char wlds[96 * WROWC * 16];   // 13824 B

    const int tid = threadIdx.x;
    const int isf32 = block_detect_f32((const unsigned int*)xraw, tid, &sflag);
    const int m0 = blockIdx.x * 64;
    const int nh = blockIdx.y;                 // N cols nh*96 .. nh*96+95
    const int wave = tid >> 6, lane = tid & 63, quad = lane >> 4, l15 = lane & 15;
    const int rw = wave & 1, cw = wave >> 1;   // rows rw*32.., cols cw*48..

    const float* xf = (const float*)xraw;
    const unsigned short* xb = (const unsigned short*)xraw;
    const unsigned char* wg = (const unsigned char*)Wt;

    // W staging: 96 rows * 9 chunks = 864 chunks, guarded
    const unsigned char* wsrc[4];
    unsigned int wdst[4];
    int nw = 0;
#pragma unroll
    for (int j = 0; j < 4; ++j) {
        int c = (wave + 4 * j) * 64 + lane;
        if (c < 864) {
            int R = c / WROWC, cc = c % WROWC;
            int ccu = (cc > 7) ? 0 : cc;
            wsrc[nw] = wg + (size_t)(nh * 96 + R) * 2048 + ccu * 16;
            wdst[nw] = c * 16;
            ++nw;
        }
    }

    // x reg staging role: thread -> row xr (0..63), 16 cols at xc
    const int xr = tid >> 2, xc = (tid & 3) * 16;
    float4 px[4];
    uint4  pxb[2];
    auto ldx = [&](int k0) {
        if (isf32) {
            const float* g = xf + (size_t)(m0 + xr) * DIN + k0 + xc;
#pragma unroll
            for (int j = 0; j < 4; ++j) px[j] = *(const float4*)(g + j * 4);
        } else {
            const unsigned short* g = xb + (size_t)(m0 + xr) * DIN + k0 + xc;
            pxb[0] = *(const uint4*)(g + 0);
            pxb[1] = *(const uint4*)(g + 8);
        }
    };

    f32x4 acc[2][3];
#pragma unroll
    for (int rt = 0; rt < 2; ++rt)
#pragma unroll
        for (int ct = 0; ct < 3; ++ct)
            acc[rt][ct] = (f32x4){0.f, 0.f, 0.f, 0.f};

    ldx(0);
    size_t woff = 0;
    for (int it = 0; it < 16; ++it) {
        __syncthreads();   // previous compute done reading LDS
        if (isf32) {
            unsigned short t[16];
#pragma unroll
            for (int j = 0; j < 4; ++j) {
                t[j * 4 + 0] = f2bf(px[j].x); t[j * 4 + 1] = f2bf(px[j].y);
                t[j * 4 + 2] = f2bf(px[j].z); t[j * 4 + 3] = f2bf(px[j].w);
            }
            *(uint4*)&xs[xr * XR + xc + 0] = *(uint4*)&t[0];
            *(uint4*)&xs[xr * XR + xc + 8] = *(uint4*)&t[8];
        } else {
            *(uint4*)&xs[xr * XR + xc + 0] = pxb[0];
            *(uint4*)&xs[xr * XR + xc + 8] = pxb[1];
        }
        for (int j = 0; j < nw; ++j) async16(&wlds[wdst[j]], wsrc[j] + woff);
        woff += 128;
        __syncthreads();   // staging visible (barrier drains DMA)

        if (it < 15) ldx((it + 1) * 64);   // overlap next x load with compute

#pragma unroll
        for (int ks = 0; ks < 2; ++ks) {
            bf16x8 a[2], b[3];
#pragma unroll
            for (int rt = 0; rt < 2; ++rt)
                a[rt] = *(const bf16x8*)
                    &xs[(rw * 32 + rt * 16 + l15) * XR + ks * 32 + quad * 8];
#pragma unroll
            for (int ct = 0; ct < 3; ++ct)
                b[ct] = *(const bf16x8*)
                    &wlds[(cw * 48 + ct * 16 + l15) * (WROWC * 16) + ks * 64 + quad * 16];
#pragma unroll
            for (int rt = 0; rt < 2; ++rt)
#pragma unroll
                for (int ct = 0; ct < 3; ++ct)
                    acc[rt][ct] = __builtin_amdgcn_mfma_f32_16x16x32_bf16(
                        a[rt], b[ct], acc[rt][ct], 0, 0, 0);
        }
    }

    // epilogue: D[row=quad*4+reg][col=l15]
#pragma unroll
    for (int rt = 0; rt < 2; ++rt)
#pragma unroll
        for (int ct = 0; ct < 3; ++ct) {
            int n = nh * 96 + cw * 48 + ct * 16 + l15;
            int wsel = n >> 6, nn = n & 63;
#pragma unroll
            for (int reg = 0; reg < 4; ++reg) {
                int m = m0 + rw * 32 + rt * 16 + quad * 4 + reg;
                unsigned short bv = f2bf(acc[rt][ct][reg]);
                if (wsel == 0)      qbuf[(size_t)m * HH + nn] = bv;
                else if (wsel == 1) kbuf[(size_t)m * HH + nn] = bv;
                else {
                    int bb = m >> 11, t = m & 2047;
                    vtbuf[((size_t)bb * HH + nn) * TT + t] = bv;
                }
            }
        }
}

// ------------------------------------------------------------------
// Split-column flash attention with FUSED combine: last chunk-block
// of each (b, row-tile) sums the partials and writes the output.
// grid (80, 8). Fixed exponent shift (partials directly summable).
// ------------------------------------------------------------------
__global__ __launch_bounds__(256) void attn_kernel(
    const unsigned short* __restrict__ rowbuf,  // k-proj [b][t][h]
    const unsigned short* __restrict__ colbuf,  // q-proj [b][s][h]
    const unsigned short* __restrict__ vtbuf,   // [b][h][s]
    float* __restrict__ O_part,                 // [slot][64][64]
    float* __restrict__ l_part,                 // [slot][64]
    int* __restrict__ ctr,                      // [8][32] counters (pre-zeroed)
    const unsigned int* __restrict__ xw,
    void* __restrict__ outraw) {

    __shared__ int sflag;
    __shared__ __align__(16) unsigned short Qr_s[64][72];
    __shared__ __align__(16) unsigned short Kc_s[64][72];
    __shared__ __align__(16) unsigned short Vt_s[64][72];
    __shared__ __align__(16) unsigned short P_s[4][16][72];
    __shared__ int slast;

    const int tid  = threadIdx.x;
    const int isf32 = block_detect_f32(xw, tid, &sflag);
    const int bx   = blockIdx.x;   // 0..79
    const int b    = blockIdx.y;
    int rt, ch;
    if (bx < 8)       { rt = bx;                 ch = 0; }
    else if (bx < 24) { rt = 8 + ((bx - 8) >> 1);  ch = (bx - 8) & 1; }
    else if (bx < 48) { rt = 16 + (bx - 24) / 3;   ch = (bx - 24) % 3; }
    else              { rt = 24 + ((bx - 48) >> 2); ch = (bx - 48) & 3; }
    const int nct = min(8, rt + 1 - ch * 8);
    const int t0 = rt * 64;
    const int slot = b * 80 + bx;

    const int wave = tid >> 6, lane = tid & 63, quad = lane >> 4, l15 = lane & 15;
    const int sr = tid >> 2, sc = (tid & 3) * 16;

    {
        const uint4* g = (const uint4*)(rowbuf + ((size_t)b * TT + t0 + sr) * HH + sc);
        *(uint4*)&Qr_s[sr][sc + 0] = g[0];
        *(uint4*)&Qr_s[sr][sc + 8] = g[1];
    }

    f32x4 o[4];
#pragma unroll
    for (int c = 0; c < 4; ++c) o[c] = (f32x4){0.f, 0.f, 0.f, 0.f};
    float ls[4] = {0.f, 0.f, 0.f, 0.f};

    const float SCL2 = 0.125f * 1.4426950408889634f;  // H^-0.5 * log2(e)

    for (int i = 0; i < nct; ++i) {
        const int stc = ch * 8 + i;
        const int s0 = stc * 64;
        {
            const uint4* gk = (const uint4*)(colbuf + ((size_t)b * TT + s0 + sr) * HH + sc);
            uint4 k0 = gk[0], k1 = gk[1];
            const uint4* gv = (const uint4*)(vtbuf + ((size_t)b * HH + sr) * TT + s0 + sc);
            uint4 v0 = gv[0], v1 = gv[1];
            *(uint4*)&Kc_s[sr][sc + 0] = k0;
            *(uint4*)&Kc_s[sr][sc + 8] = k1;
            *(uint4*)&Vt_s[sr][sc + 0] = v0;
            *(uint4*)&Vt_s[sr][sc + 8] = v1;
        }
        __syncthreads();

        f32x4 scf[4];
#pragma unroll
        for (int c = 0; c < 4; ++c) scf[c] = (f32x4){0.f, 0.f, 0.f, 0.f};
#pragma unroll
        for (int ks = 0; ks < 2; ++ks) {
            bf16x8 a = *(const bf16x8*)&Qr_s[wave * 16 + l15][ks * 32 + quad * 8];
#pragma unroll
            for (int c = 0; c < 4; ++c) {
                bf16x8 bb = *(const bf16x8*)&Kc_s[c * 16 + l15][ks * 32 + quad * 8];
                scf[c] = __builtin_amdgcn_mfma_f32_16x16x32_bf16(a, bb, scf[c], 0, 0, 0);
            }
        }

        const bool diag = (stc == rt);
#pragma unroll
        for (int r = 0; r < 4; ++r) {
            const int tg = t0 + wave * 16 + quad * 4 + r;
#pragma unroll
            for (int c = 0; c < 4; ++c) {
                float arg = fmaf(scf[c][r], SCL2, -30.f);
                if (diag && (s0 + c * 16 + l15) > tg) arg = -200.f;
                float p = __builtin_amdgcn_exp2f(arg);
                P_s[wave][quad * 4 + r][c * 16 + l15] = f2bf(p);
                ls[r] += p;
            }
        }
        // P_s is per-wave: intra-wave LDS RAW, compiler lgkmcnt suffices.
#pragma unroll
        for (int ks = 0; ks < 2; ++ks) {
            bf16x8 ap = *(const bf16x8*)&P_s[wave][l15][ks * 32 + quad * 8];
#pragma unroll
            for (int c = 0; c < 4; ++c) {
                bf16x8 bv = *(const bf16x8*)&Vt_s[c * 16 + l15][ks * 32 + quad * 8];
                o[c] = __builtin_amdgcn_mfma_f32_16x16x32_bf16(ap, bv, o[c], 0, 0, 0);
            }
        }
        __syncthreads();   // Kc/Vt consumed; safe to restage
    }

    // per-row l: reduce over the 16 l15 lanes
#pragma unroll
    for (int r = 0; r < 4; ++r) {
#pragma unroll
        for (int off = 1; off < 16; off <<= 1) ls[r] += __shfl_xor(ls[r], off);
    }
    if (l15 == 0) {
#pragma unroll
        for (int r = 0; r < 4; ++r)
            l_part[(size_t)slot * 64 + wave * 16 + quad * 4 + r] = ls[r];
    }
#pragma unroll
    for (int c = 0; c < 4; ++c)
#pragma unroll
        for (int r = 0; r < 4; ++r)
            O_part[(size_t)slot * 4096 + (wave * 16 + quad * 4 + r) * 64 + c * 16 + l15] = o[c][r];

    // ---- fused combine: last-arriving chunk block reduces ----
    const int nch = rt / 8 + 1;
    __threadfence();
    __syncthreads();
    if (tid == 0) {
        int prev = atomicAdd(&ctr[b * 32 + rt], 1);
        slast = (prev == nch - 1) ? 1 : 0;
    }
    __syncthreads();
    if (!slast) return;
    __threadfence();   // acquire: invalidate L1 before reading peers' partials

    const int off = (rt < 8) ? rt : (rt < 16) ? 8 + 2 * (rt - 8)
                   : (rt < 24) ? 24 + 3 * (rt - 16) : 48 + 4 * (rt - 24);
    const int slot0 = b * 80 + off;
    const int row = tid >> 2, cb = (tid & 3) * 16;
    f32x4 a[4];
#pragma unroll
    for (int q = 0; q < 4; ++q) a[q] = (f32x4){0.f, 0.f, 0.f, 0.f};
    float l = 0.f;
    for (int j = 0; j < nch; ++j) {
        const f32x4* p = (const f32x4*)(O_part + (size_t)(slot0 + j) * 4096 + row * 64 + cb);
#pragma unroll
        for (int q = 0; q < 4; ++q) a[q] += p[q];
        l += l_part[(size_t)(slot0 + j) * 64 + row];
    }
    const float inv = 1.f / l;
    const size_t base = ((size_t)b * TT + rt * 64 + row) * HH + cb;
    if (isf32) {
        float* outf = (float*)outraw;
#pragma unroll
        for (int q = 0; q < 4; ++q) {
            f32x4 v = a[q] * inv;
            *(f32x4*)(outf + base + q * 4) = v;
        }
    } else {
        unsigned short h[16];
#pragma unroll
        for (int q = 0; q < 4; ++q)
#pragma unroll
            for (int e = 0; e < 4; ++e) h[q * 4 + e] = f2bf(a[q][e] * inv);
        unsigned short* outb = (unsigned short*)outraw;
        *(uint4*)(outb + base + 0) = *(uint4*)&h[0];
        *(uint4*)(outb + base + 8) = *(uint4*)&h[8];
    }
}

extern "C" void kernel_launch(void* const* d_in, const int* in_sizes, int n_in,
                              void* d_out, int out_size, void* d_ws, size_t ws_size,
                              hipStream_t stream) {
    const void* x  = d_in[0];
    const void* Wq = d_in[1];
    const void* Wk = d_in[2];
    const void* Wv = d_in[3];
    unsigned short* ws = (unsigned short*)d_ws;

    unsigned short* qbuf  = ws;                          // 2 MB
    unsigned short* kbuf  = ws + (size_t)MM * HH;        // 2 MB
    unsigned short* vtbuf = ws + (size_t)2 * MM * HH;    // 2 MB
    unsigned short* wtbuf = ws + (size_t)3 * MM * HH;    // 384 KB
    float* O_part = (float*)(ws + (size_t)3 * MM * HH + 3 * 65536);  // 10.5 MB
    float* l_part = O_part + (size_t)640 * 4096;                      // 164 KB
    int*   ctr    = (int*)(l_part + 640 * 64);                        // 1 KB

    hipLaunchKernelGGL(transpose_w_kernel, dim3(48), dim3(256), 0, stream,
                       Wq, Wk, Wv, (const unsigned int*)x, wtbuf, ctr);
    hipLaunchKernelGGL(proj_kernel, dim3(256, 2), dim3(256), 0, stream,
                       x, wtbuf, qbuf, kbuf, vtbuf);
    hipLaunchKernelGGL(attn_kernel, dim3(80, 8), dim3(256), 0, stream,
                       kbuf, qbuf, vtbuf, O_part, l_part, ctr,
                       (const unsigned int*)x, d_out);
}

// Round 9
// 146.561 us; speedup vs baseline: 1.9027x; 1.9027x over previous
//
#include <hip/hip_runtime.h>

typedef __bf16 bf16_t;
typedef bf16_t bf16x8 __attribute__((ext_vector_type(8)));
typedef float f32x4 __attribute__((ext_vector_type(4)));

#define NB 8
#define TT 2048
#define DIN 1024
#define HH 64
#define MM (NB * TT)

__device__ __forceinline__ unsigned short f2bf(float f) {
    unsigned int u = __float_as_uint(f);
    u += 0x7fffu + ((u >> 16) & 1u);   // round-to-nearest-even
    return (unsigned short)(u >> 16);
}

// async global->LDS, 16B per lane. LDS dest = base + lane*16 (linear);
// global src may be per-lane (16B-aligned). Exec-masked.
__device__ __forceinline__ void async16(void* l, const void* g) {
    __builtin_amdgcn_global_load_lds(
        (const __attribute__((address_space(1))) unsigned int*)g,
        (__attribute__((address_space(3))) unsigned int*)l, 16, 0, 0);
}

// Per-block dtype probe: low-bf16 exponent field of x words.
// fp32 data -> ~20% in range; bf16 -> ~100%. Returns 1 if fp32.
__device__ __forceinline__ int block_detect_f32(const unsigned int* __restrict__ xw,
                                                int tid, int* sflag) {
    if (tid < 64) {
        unsigned int u = xw[tid];
        unsigned int e = (u >> 7) & 0xFFu;
        unsigned long long m = __ballot(e >= 100u && e <= 150u);
        if (tid == 0) *sflag = (__popcll(m) < 48) ? 1 : 0;
    }
    __syncthreads();
    return *sflag;
}

// ------------------------------------------------------------------
// LDS-tiled W transpose: Wt[w*64+n][k] = W_w[k][n], bf16.
// ------------------------------------------------------------------
__global__ __launch_bounds__(256) void transpose_w_kernel(
    const void* __restrict__ Wq, const void* __restrict__ Wk,
    const void* __restrict__ Wv, const unsigned int* __restrict__ xw,
    unsigned short* __restrict__ Wt) {
    __shared__ int sflag;
    __shared__ unsigned short ts[64][68];
    const int tid = threadIdx.x;
    const int isf32 = block_detect_f32(xw, tid, &sflag);
    const int w = blockIdx.x >> 4, kt = blockIdx.x & 15;
    const void* W = (w == 0) ? Wq : (w == 1) ? Wk : Wv;
    const int kk = tid >> 4, nn = (tid & 15) * 4;
#pragma unroll
    for (int j = 0; j < 4; ++j) {
        int k = kk + j * 16;
        if (isf32) {
            float4 f = *(const float4*)((const float*)W + (size_t)(kt * 64 + k) * 64 + nn);
            ts[k][nn + 0] = f2bf(f.x); ts[k][nn + 1] = f2bf(f.y);
            ts[k][nn + 2] = f2bf(f.z); ts[k][nn + 3] = f2bf(f.w);
        } else {
            *(uint2*)&ts[k][nn] =
                *(const uint2*)((const unsigned short*)W + (size_t)(kt * 64 + k) * 64 + nn);
        }
    }
    __syncthreads();
    const int n = tid >> 2, k0 = (tid & 3) * 16;
    unsigned short tmp[16];
#pragma unroll
    for (int j = 0; j < 16; ++j) tmp[j] = ts[k0 + j][n];
    unsigned short* dst = Wt + (size_t)(w * 64 + n) * 1024 + kt * 64 + k0;
    *(uint4*)(dst + 0) = *(uint4*)&tmp[0];
    *(uint4*)(dst + 8) = *(uint4*)&tmp[8];
}

// ------------------------------------------------------------------
// Fused QKV projection v6: cut LDS insts/MFMA. Block = M-64 x N-96
// (nh = blockIdx.y), grid (256,2) = 512 blocks = 2/CU. Wave-tile
// 32x48: per wave-iter 4 A + 6 B ds_read_b128 -> 12 MFMA. x converted
// fp32->bf16 BEFORE LDS (reg->cvt->ds_write_b128). W via async16.
// ------------------------------------------------------------------
#define XR 72      /* x LDS row stride in bf16 elems (144 B) */
#define WROWC 9    /* W LDS row = 9 chunks = 144 B (128 payload) */

__global__ __launch_bounds__(256, 2) void proj_kernel(
    const void* __restrict__ xraw, const unsigned short* __restrict__ Wt,
    unsigned short* __restrict__ qbuf, unsigned short* __restrict__ kbuf,
    unsigned short* __restrict__ vtbuf) {
    __shared__ int sflag;
    __shared__ __align__(16) unsigned short xs[64 * XR];            // 9216 B
    __shared__ __align__(16) unsigned char wlds[96 * WROWC * 16];   // 13824 B

    const int tid = threadIdx.x;
    const int isf32 = block_detect_f32((const unsigned int*)xraw, tid, &sflag);
    const int m0 = blockIdx.x * 64;
    const int nh = blockIdx.y;                 // N cols nh*96 .. nh*96+95
    const int wave = tid >> 6, lane = tid & 63, quad = lane >> 4, l15 = lane & 15;
    const int rw = wave & 1, cw = wave >> 1;   // rows rw*32.., cols cw*48..

    const float* xf = (const float*)xraw;
    const unsigned short* xb = (const unsigned short*)xraw;
    const unsigned char* wg = (const unsigned char*)Wt;

    // W staging: 96 rows * 9 chunks = 864 chunks, guarded
    const unsigned char* wsrc[4];
    unsigned int wdst[4];
    int nw = 0;
#pragma unroll
    for (int j = 0; j < 4; ++j) {
        int c = (wave + 4 * j) * 64 + lane;
        if (c < 864) {
            int R = c / WROWC, cc = c % WROWC;
            int ccu = (cc > 7) ? 0 : cc;
            wsrc[nw] = wg + (size_t)(nh * 96 + R) * 2048 + ccu * 16;
            wdst[nw] = c * 16;
            ++nw;
        }
    }

    // x reg staging role: thread -> row xr (0..63), 16 cols at xc
    const int xr = tid >> 2, xc = (tid & 3) * 16;
    float4 px[4];
    uint4  pxb[2];
    auto ldx = [&](int k0) {
        if (isf32) {
            const float* g = xf + (size_t)(m0 + xr) * DIN + k0 + xc;
#pragma unroll
            for (int j = 0; j < 4; ++j) px[j] = *(const float4*)(g + j * 4);
        } else {
            const unsigned short* g = xb + (size_t)(m0 + xr) * DIN + k0 + xc;
            pxb[0] = *(const uint4*)(g + 0);
            pxb[1] = *(const uint4*)(g + 8);
        }
    };

    f32x4 acc[2][3];
#pragma unroll
    for (int rt = 0; rt < 2; ++rt)
#pragma unroll
        for (int ct = 0; ct < 3; ++ct)
            acc[rt][ct] = (f32x4){0.f, 0.f, 0.f, 0.f};

    ldx(0);
    size_t woff = 0;
    for (int it = 0; it < 16; ++it) {
        __syncthreads();   // previous compute done reading LDS
        if (isf32) {
            unsigned short t[16];
#pragma unroll
            for (int j = 0; j < 4; ++j) {
                t[j * 4 + 0] = f2bf(px[j].x); t[j * 4 + 1] = f2bf(px[j].y);
                t[j * 4 + 2] = f2bf(px[j].z); t[j * 4 + 3] = f2bf(px[j].w);
            }
            *(uint4*)&xs[xr * XR + xc + 0] = *(uint4*)&t[0];
            *(uint4*)&xs[xr * XR + xc + 8] = *(uint4*)&t[8];
        } else {
            *(uint4*)&xs[xr * XR + xc + 0] = pxb[0];
            *(uint4*)&xs[xr * XR + xc + 8] = pxb[1];
        }
        for (int j = 0; j < nw; ++j) async16(&wlds[wdst[j]], wsrc[j] + woff);
        woff += 128;
        __syncthreads();   // staging visible (barrier drains DMA)

        if (it < 15) ldx((it + 1) * 64);   // overlap next x load with compute

#pragma unroll
        for (int ks = 0; ks < 2; ++ks) {
            bf16x8 a[2], b[3];
#pragma unroll
            for (int rt = 0; rt < 2; ++rt)
                a[rt] = *(const bf16x8*)
                    &xs[(rw * 32 + rt * 16 + l15) * XR + ks * 32 + quad * 8];
#pragma unroll
            for (int ct = 0; ct < 3; ++ct)
                b[ct] = *(const bf16x8*)
                    &wlds[(cw * 48 + ct * 16 + l15) * (WROWC * 16) + ks * 64 + quad * 16];
#pragma unroll
            for (int rt = 0; rt < 2; ++rt)
#pragma unroll
                for (int ct = 0; ct < 3; ++ct)
                    acc[rt][ct] = __builtin_amdgcn_mfma_f32_16x16x32_bf16(
                        a[rt], b[ct], acc[rt][ct], 0, 0, 0);
        }
    }

    // epilogue: D[row=quad*4+reg][col=l15]
#pragma unroll
    for (int rt = 0; rt < 2; ++rt)
#pragma unroll
        for (int ct = 0; ct < 3; ++ct) {
            int n = nh * 96 + cw * 48 + ct * 16 + l15;
            int wsel = n >> 6, nn = n & 63;
#pragma unroll
            for (int reg = 0; reg < 4; ++reg) {
                int m = m0 + rw * 32 + rt * 16 + quad * 4 + reg;
                unsigned short bv = f2bf(acc[rt][ct][reg]);
                if (wsel == 0)      qbuf[(size_t)m * HH + nn] = bv;
                else if (wsel == 1) kbuf[(size_t)m * HH + nn] = bv;
                else {
                    int bb = m >> 11, t = m & 2047;
                    vtbuf[((size_t)bb * HH + nn) * TT + t] = bv;
                }
            }
        }
}

// ------------------------------------------------------------------
// Split-column flash attention, FIXED exponent shift (no online max;
// partials are directly summable). grid (80, 8). NO fences/atomics —
// combine is a separate kernel (kernel boundary = free device-scope
// release; in-kernel __threadfence storm cost ~130 us in R8).
// ------------------------------------------------------------------
__global__ __launch_bounds__(256) void attn_kernel(
    const unsigned short* __restrict__ rowbuf,  // k-proj [b][t][h]
    const unsigned short* __restrict__ colbuf,  // q-proj [b][s][h]
    const unsigned short* __restrict__ vtbuf,   // [b][h][s]
    float* __restrict__ O_part,                 // [slot][64][64]
    float* __restrict__ l_part) {               // [slot][64]

    __shared__ __align__(16) unsigned short Qr_s[64][72];
    __shared__ __align__(16) unsigned short Kc_s[64][72];
    __shared__ __align__(16) unsigned short Vt_s[64][72];
    __shared__ __align__(16) unsigned short P_s[4][16][72];

    const int tid  = threadIdx.x;
    const int bx   = blockIdx.x;   // 0..79
    const int b    = blockIdx.y;
    int rt, ch;
    if (bx < 8)       { rt = bx;                 ch = 0; }
    else if (bx < 24) { rt = 8 + ((bx - 8) >> 1);  ch = (bx - 8) & 1; }
    else if (bx < 48) { rt = 16 + (bx - 24) / 3;   ch = (bx - 24) % 3; }
    else              { rt = 24 + ((bx - 48) >> 2); ch = (bx - 48) & 3; }
    const int nct = min(8, rt + 1 - ch * 8);
    const int t0 = rt * 64;
    const int slot = b * 80 + bx;

    const int wave = tid >> 6, lane = tid & 63, quad = lane >> 4, l15 = lane & 15;
    const int sr = tid >> 2, sc = (tid & 3) * 16;

    {
        const uint4* g = (const uint4*)(rowbuf + ((size_t)b * TT + t0 + sr) * HH + sc);
        *(uint4*)&Qr_s[sr][sc + 0] = g[0];
        *(uint4*)&Qr_s[sr][sc + 8] = g[1];
    }

    f32x4 o[4];
#pragma unroll
    for (int c = 0; c < 4; ++c) o[c] = (f32x4){0.f, 0.f, 0.f, 0.f};
    float ls[4] = {0.f, 0.f, 0.f, 0.f};

    const float SCL2 = 0.125f * 1.4426950408889634f;  // H^-0.5 * log2(e)

    for (int i = 0; i < nct; ++i) {
        const int stc = ch * 8 + i;
        const int s0 = stc * 64;
        {
            const uint4* gk = (const uint4*)(colbuf + ((size_t)b * TT + s0 + sr) * HH + sc);
            uint4 k0 = gk[0], k1 = gk[1];
            const uint4* gv = (const uint4*)(vtbuf + ((size_t)b * HH + sr) * TT + s0 + sc);
            uint4 v0 = gv[0], v1 = gv[1];
            *(uint4*)&Kc_s[sr][sc + 0] = k0;
            *(uint4*)&Kc_s[sr][sc + 8] = k1;
            *(uint4*)&Vt_s[sr][sc + 0] = v0;
            *(uint4*)&Vt_s[sr][sc + 8] = v1;
        }
        __syncthreads();

        f32x4 scf[4];
#pragma unroll
        for (int c = 0; c < 4; ++c) scf[c] = (f32x4){0.f, 0.f, 0.f, 0.f};
#pragma unroll
        for (int ks = 0; ks < 2; ++ks) {
            bf16x8 a = *(const bf16x8*)&Qr_s[wave * 16 + l15][ks * 32 + quad * 8];
#pragma unroll
            for (int c = 0; c < 4; ++c) {
                bf16x8 bb = *(const bf16x8*)&Kc_s[c * 16 + l15][ks * 32 + quad * 8];
                scf[c] = __builtin_amdgcn_mfma_f32_16x16x32_bf16(a, bb, scf[c], 0, 0, 0);
            }
        }

        const bool diag = (stc == rt);
#pragma unroll
        for (int r = 0; r < 4; ++r) {
            const int tg = t0 + wave * 16 + quad * 4 + r;
#pragma unroll
            for (int c = 0; c < 4; ++c) {
                float arg = fmaf(scf[c][r], SCL2, -30.f);
                if (diag && (s0 + c * 16 + l15) > tg) arg = -200.f;
                float p = __builtin_amdgcn_exp2f(arg);
                P_s[wave][quad * 4 + r][c * 16 + l15] = f2bf(p);
                ls[r] += p;
            }
        }
        // P_s is per-wave: intra-wave LDS RAW, compiler lgkmcnt suffices.
#pragma unroll
        for (int ks = 0; ks < 2; ++ks) {
            bf16x8 ap = *(const bf16x8*)&P_s[wave][l15][ks * 32 + quad * 8];
#pragma unroll
            for (int c = 0; c < 4; ++c) {
                bf16x8 bv = *(const bf16x8*)&Vt_s[c * 16 + l15][ks * 32 + quad * 8];
                o[c] = __builtin_amdgcn_mfma_f32_16x16x32_bf16(ap, bv, o[c], 0, 0, 0);
            }
        }
        __syncthreads();   // Kc/Vt consumed; safe to restage
    }

    // per-row l: reduce over the 16 l15 lanes (once, at the end)
#pragma unroll
    for (int r = 0; r < 4; ++r) {
#pragma unroll
        for (int off = 1; off < 16; off <<= 1) ls[r] += __shfl_xor(ls[r], off);
    }
    if (l15 == 0) {
#pragma unroll
        for (int r = 0; r < 4; ++r)
            l_part[(size_t)slot * 64 + wave * 16 + quad * 4 + r] = ls[r];
    }
#pragma unroll
    for (int c = 0; c < 4; ++c)
#pragma unroll
        for (int r = 0; r < 4; ++r)
            O_part[(size_t)slot * 4096 + (wave * 16 + quad * 4 + r) * 64 + c * 16 + l15] = o[c][r];
}

// ------------------------------------------------------------------
// Combine partials: out = (sum O_part) / (sum l_part). grid (32, 8).
// ------------------------------------------------------------------
__global__ __launch_bounds__(256) void combine_kernel(
    const float* __restrict__ O_part, const float* __restrict__ l_part,
    const unsigned int* __restrict__ xw, void* __restrict__ outraw) {
    __shared__ int sflag;
    const int tid = threadIdx.x;
    const int isf32 = block_detect_f32(xw, tid, &sflag);
    const int rt = blockIdx.x, b = blockIdx.y;
    const int nch = rt / 8 + 1;
    const int off = (rt < 8) ? rt : (rt < 16) ? 8 + 2 * (rt - 8)
                   : (rt < 24) ? 24 + 3 * (rt - 16) : 48 + 4 * (rt - 24);
    const int slot0 = b * 80 + off;

    const int row = tid >> 2, cb = (tid & 3) * 16;
    f32x4 a[4];
#pragma unroll
    for (int q = 0; q < 4; ++q) a[q] = (f32x4){0.f, 0.f, 0.f, 0.f};
    float l = 0.f;
    for (int j = 0; j < nch; ++j) {
        const f32x4* p = (const f32x4*)(O_part + (size_t)(slot0 + j) * 4096 + row * 64 + cb);
#pragma unroll
        for (int q = 0; q < 4; ++q) a[q] += p[q];
        l += l_part[(size_t)(slot0 + j) * 64 + row];
    }
    const float inv = 1.f / l;
    const size_t base = ((size_t)b * TT + rt * 64 + row) * HH + cb;
    if (isf32) {
        float* outf = (float*)outraw;
#pragma unroll
        for (int q = 0; q < 4; ++q) {
            f32x4 v = a[q] * inv;
            *(f32x4*)(outf + base + q * 4) = v;
        }
    } else {
        unsigned short h[16];
#pragma unroll
        for (int q = 0; q < 4; ++q)
#pragma unroll
            for (int e = 0; e < 4; ++e) h[q * 4 + e] = f2bf(a[q][e] * inv);
        unsigned short* outb = (unsigned short*)outraw;
        *(uint4*)(outb + base + 0) = *(uint4*)&h[0];
        *(uint4*)(outb + base + 8) = *(uint4*)&h[8];
    }
}

extern "C" void kernel_launch(void* const* d_in, const int* in_sizes, int n_in,
                              void* d_out, int out_size, void* d_ws, size_t ws_size,
                              hipStream_t stream) {
    const void* x  = d_in[0];
    const void* Wq = d_in[1];
    const void* Wk = d_in[2];
    const void* Wv = d_in[3];
    unsigned short* ws = (unsigned short*)d_ws;

    unsigned short* qbuf  = ws;                          // 2 MB
    unsigned short* kbuf  = ws + (size_t)MM * HH;        // 2 MB
    unsigned short* vtbuf = ws + (size_t)2 * MM * HH;    // 2 MB
    unsigned short* wtbuf = ws + (size_t)3 * MM * HH;    // 384 KB
    float* O_part = (float*)(ws + (size_t)3 * MM * HH + 3 * 65536);  // 10.5 MB
    float* l_part = O_part + (size_t)640 * 4096;                      // 164 KB

    hipLaunchKernelGGL(transpose_w_kernel, dim3(48), dim3(256), 0, stream,
                       Wq, Wk, Wv, (const unsigned int*)x, wtbuf);
    hipLaunchKernelGGL(proj_kernel, dim3(256, 2), dim3(256), 0, stream,
                       x, wtbuf, qbuf, kbuf, vtbuf);
    hipLaunchKernelGGL(attn_kernel, dim3(80, 8), dim3(256), 0, stream,
                       kbuf, qbuf, vtbuf, O_part, l_part);
    hipLaunchKernelGGL(combine_kernel, dim3(32, 8), dim3(256), 0, stream,
                       O_part, l_part, (const unsigned int*)x, d_out);
}